// Round 2
// baseline (832.063 us; speedup 1.0000x reference)
//
#include <hip/hip_runtime.h>
#include <math.h>

// ---------------------------------------------------------------------------
// GCN 2-layer forward on MI355X. Round 10: L2-resident gathers via
// feature-chunking.
//   Evidence (r8/r9): aggfused pinned at 3.5 TB/s with ~500 MB HBM FETCH;
//   MLP increases didn't move it -> random-gather path saturated. Fix the
//   traffic, not the latency:
//   * h1 stored chunk-major: h1c[16][(N+1)][16 feats] bf16, pre-scaled by
//     dv_src. One 16-feat chunk = 3.2 MB -> fits a 4 MB XCD L2. aggchunk's
//     grid is chunk-major so ~1.3 chunks are live at a time -> gathers hit L2.
//   * Edge records shrink to src-only int32 (weights algebraically removed:
//     rows pre-scaled by dv_src at producer, dv_dst applied at consumer;
//     clamped slots gather a zeroed pad row instead of w=0).
//   * aggchunk writes relu(dv_d*sum + b1) to agg1[N][256]; new lean gemm2
//     (agg1 @ W2, dv-prescaled epilog) replaces the old fused phase-2.
//   * agg64: src-only records + zero-row clamp + dv epilog.
// ---------------------------------------------------------------------------

typedef __attribute__((ext_vector_type(8))) short bf16x8;
typedef __attribute__((ext_vector_type(4))) float f32x4;

__device__ inline unsigned short f2bf(float f) {
    union { float f; unsigned int u; } v; v.f = f;
    unsigned int r = v.u + 0x7fffu + ((v.u >> 16) & 1u);  // RNE
    return (unsigned short)(r >> 16);
}
__device__ inline float bf2f_lo(unsigned int u) {
    union { unsigned int u; float f; } v; v.u = u << 16; return v.f;
}
__device__ inline float bf2f_hi(unsigned int u) {
    union { unsigned int u; float f; } v; v.u = u & 0xffff0000u; return v.f;
}

// unpack uint4 (8 bf16) and ADD into acc[8] (rows are pre-scaled; no weight)
__device__ inline void acc8a(float* acc, uint4 q) {
    acc[0] += bf2f_lo(q.x); acc[1] += bf2f_hi(q.x);
    acc[2] += bf2f_lo(q.y); acc[3] += bf2f_hi(q.y);
    acc[4] += bf2f_lo(q.z); acc[5] += bf2f_hi(q.z);
    acc[6] += bf2f_lo(q.w); acc[7] += bf2f_hi(q.w);
}

// ---------------- CSR build ----------------
__global__ __launch_bounds__(256) void deg_kernel(
    const int* __restrict__ dst, int E, int* __restrict__ cnt) {
    int e = blockIdx.x * blockDim.x + threadIdx.x;
    if (e < E) atomicAdd(&cnt[dst[e]], 1);
}

// dv[n] = rsqrt(deg_incl_self); also zeroes the pad rows of h1c and h2s.
__global__ __launch_bounds__(256) void dv_kernel(
    const int* __restrict__ cnt, float* __restrict__ dv,
    unsigned short* __restrict__ h1c, unsigned short* __restrict__ h2s,
    int N) {
    int i = blockIdx.x * 256 + threadIdx.x;
    if (i < N) dv[i] = rsqrtf((float)cnt[i] + 1.0f);
    if (blockIdx.x == 0) {
        int t = threadIdx.x;
        // h1c pad rows: 16 chunks x 16 shorts at node N
        h1c[((size_t)(t >> 4) * (N + 1) + N) * 16 + (t & 15)] = 0;
        if (t < 64) h2s[(size_t)N * 64 + t] = 0;
    }
}

__global__ __launch_bounds__(256) void scan_part1_kernel(
    const int* __restrict__ cnt, int* __restrict__ bsum, int N) {
    __shared__ int s[256];
    const int tid = threadIdx.x;
    int base = blockIdx.x * 1024 + tid * 4;
    int v = 0;
#pragma unroll
    for (int j = 0; j < 4; ++j)
        if (base + j < N) v += cnt[base + j];
    s[tid] = v;
    __syncthreads();
    for (int off = 128; off > 0; off >>= 1) {
        if (tid < off) s[tid] += s[tid + off];
        __syncthreads();
    }
    if (tid == 0) bsum[blockIdx.x] = s[0];
}

__global__ __launch_bounds__(1024) void scan_part2_kernel(
    const int* __restrict__ bsum, int* __restrict__ boffs, int NB,
    int* __restrict__ row_ptr, int N) {
    __shared__ int s[1024];
    const int tid = threadIdx.x;
    int v = (tid < NB) ? bsum[tid] : 0;
    s[tid] = v;
    __syncthreads();
    for (int off = 1; off < 1024; off <<= 1) {
        int t = (tid >= off) ? s[tid - off] : 0;
        __syncthreads();
        if (tid >= off) s[tid] += t;
        __syncthreads();
    }
    if (tid < NB) boffs[tid] = s[tid] - v;  // exclusive
    if (tid == 1023) row_ptr[N] = s[1023];  // grand total
}

__global__ __launch_bounds__(256) void scan_part3_kernel(
    const int* __restrict__ cnt, const int* __restrict__ boffs,
    int* __restrict__ row_ptr, int N) {
    __shared__ int s[256];
    const int tid = threadIdx.x;
    int base = blockIdx.x * 1024 + tid * 4;
    int c[4];
    int v = 0;
#pragma unroll
    for (int j = 0; j < 4; ++j) {
        c[j] = (base + j < N) ? cnt[base + j] : 0;
        v += c[j];
    }
    s[tid] = v;
    __syncthreads();
    for (int off = 1; off < 256; off <<= 1) {
        int t = (tid >= off) ? s[tid - off] : 0;
        __syncthreads();
        if (tid >= off) s[tid] += t;
        __syncthreads();
    }
    int run = boffs[blockIdx.x] + s[tid] - v;
#pragma unroll
    for (int j = 0; j < 4; ++j) {
        if (base + j < N) {
            row_ptr[base + j] = run;
            run += c[j];
        }
    }
}

// scatter: csr_src[row_ptr[d] + slot] = s (order within row irrelevant)
__global__ __launch_bounds__(256) void scatter_kernel(
    const int* __restrict__ src, const int* __restrict__ dst,
    const int* __restrict__ row_ptr, int* __restrict__ fill,
    int* __restrict__ csr_src, int E) {
    int e = blockIdx.x * blockDim.x + threadIdx.x;
    if (e >= E) return;
    int d = dst[e];
    int pos = row_ptr[d] + atomicAdd(&fill[d], 1);
    csr_src[pos] = src[e];
}

// ------ merged weight cast+transpose: W1t[n][k], W2t[n][k] (bf16) ----------
__global__ __launch_bounds__(256) void castw_kernel(
    const float* __restrict__ W1, const float* __restrict__ W2,
    unsigned short* __restrict__ W1t, unsigned short* __restrict__ W2t) {
    int i = blockIdx.x * 256 + threadIdx.x;
    if (i < 65536) {  // W1: 256x256
        int n = i >> 8, k = i & 255;
        W1t[i] = f2bf(W1[(size_t)k * 256 + n]);
    } else if (i < 65536 + 16384) {  // W2: 256x64 -> W2t[64][256]
        int j = i - 65536;
        int n = j >> 8, k = j & 255;
        W2t[j] = f2bf(W2[(size_t)k * 64 + n]);
    }
}

// ------- GEMM1: h1c[chunk][row][16] = bf16(dv_row * (x @ W1)), MFMA --------
// 128(M) x 256(N) tile, BK=32. Wave w owns cols [64w, 64w+64).
__global__ __launch_bounds__(256) void gemm1_kernel(
    const float* __restrict__ A, const unsigned short* __restrict__ Bt,
    const float* __restrict__ dv, unsigned short* __restrict__ C, int M) {
    __shared__ unsigned short As[128][32];   // 8 KB
    __shared__ unsigned short Bs[256][32];   // 16 KB

    const int tid = threadIdx.x;
    const int wave = tid >> 6, lane = tid & 63;
    const int quad = lane >> 4, l15 = lane & 15;
    const int m0 = blockIdx.x * 128;
    const size_t cstride = (size_t)(M + 1) * 16;  // shorts per chunk plane

    f32x4 acc[8][4] = {};

    const int arow = tid >> 1;          // 0..127
    const int akk  = (tid & 1) << 4;    // 0 or 16
    const int gr = m0 + arow;

    for (int k0 = 0; k0 < 256; k0 += 32) {
        float4 a0 = make_float4(0.f,0.f,0.f,0.f), a1 = a0, a2 = a0, a3 = a0;
        if (gr < M) {
            const float* ap = &A[(size_t)gr * 256 + k0 + akk];
            a0 = *(const float4*)&ap[0];
            a1 = *(const float4*)&ap[4];
            a2 = *(const float4*)&ap[8];
            a3 = *(const float4*)&ap[12];
        }
        bf16x8 av0, av1;
        av0[0] = (short)f2bf(a0.x); av0[1] = (short)f2bf(a0.y);
        av0[2] = (short)f2bf(a0.z); av0[3] = (short)f2bf(a0.w);
        av0[4] = (short)f2bf(a1.x); av0[5] = (short)f2bf(a1.y);
        av0[6] = (short)f2bf(a1.z); av0[7] = (short)f2bf(a1.w);
        av1[0] = (short)f2bf(a2.x); av1[1] = (short)f2bf(a2.y);
        av1[2] = (short)f2bf(a2.z); av1[3] = (short)f2bf(a2.w);
        av1[4] = (short)f2bf(a3.x); av1[5] = (short)f2bf(a3.y);
        av1[6] = (short)f2bf(a3.z); av1[7] = (short)f2bf(a3.w);
        *(bf16x8*)&As[arow][akk]     = av0;
        *(bf16x8*)&As[arow][akk + 8] = av1;

        const unsigned short* bsrc = &Bt[(size_t)tid * 256 + k0];
        *(bf16x8*)&Bs[tid][0]  = *(const bf16x8*)&bsrc[0];
        *(bf16x8*)&Bs[tid][8]  = *(const bf16x8*)&bsrc[8];
        *(bf16x8*)&Bs[tid][16] = *(const bf16x8*)&bsrc[16];
        *(bf16x8*)&Bs[tid][24] = *(const bf16x8*)&bsrc[24];
        __syncthreads();

        bf16x8 bfv[4];
#pragma unroll
        for (int nt = 0; nt < 4; ++nt)
            bfv[nt] = *(const bf16x8*)&Bs[wave * 64 + nt * 16 + l15][quad * 8];
#pragma unroll
        for (int mt = 0; mt < 8; ++mt) {
            bf16x8 af = *(const bf16x8*)&As[mt * 16 + l15][quad * 8];
#pragma unroll
            for (int nt = 0; nt < 4; ++nt)
                acc[mt][nt] = __builtin_amdgcn_mfma_f32_16x16x32_bf16(
                    af, bfv[nt], acc[mt][nt], 0, 0, 0);
        }
        __syncthreads();
    }

#pragma unroll
    for (int mt = 0; mt < 8; ++mt) {
#pragma unroll
        for (int r = 0; r < 4; ++r) {
            int grow = m0 + mt * 16 + quad * 4 + r;
            if (grow < M) {
                float sc = dv[grow];
#pragma unroll
                for (int nt = 0; nt < 4; ++nt) {
                    int chunk = wave * 4 + nt;  // col>>4
                    C[(size_t)chunk * cstride + (size_t)grow * 16 + l15] =
                        f2bf(acc[mt][nt][r] * sc);
                }
            }
        }
    }
}

// ---- aggchunk: agg1[node][chunk*16..+16) = relu(dv_d * sum + b1) ----------
// Grid chunk-major: bid = chunk*NBn + nb. Per wave: 4 nodes interleaved;
// per iter: 8 edges/node, 32B row-chunk gathers (8 lanes x dword).
__global__ __launch_bounds__(256) void aggchunk_kernel(
    const unsigned int* __restrict__ h1c,  // [16][(N+1)][8] dwords chunk-major
    const int* __restrict__ srcs, const int* __restrict__ row_ptr,
    const float* __restrict__ dv, const float* __restrict__ bias,
    unsigned short* __restrict__ agg1, int N, int NBn) {
    const int chunk = blockIdx.x / NBn;
    const int nb    = blockIdx.x % NBn;
    const int tid = threadIdx.x;
    const int wave = tid >> 6, lane = tid & 63;
    const int g = lane >> 3, c = lane & 7;
    const unsigned int* __restrict__ hc = h1c + (size_t)chunk * (N + 1) * 8;
    const int node0 = nb * 16 + wave * 4;

    int bg[4], en[4];
#pragma unroll
    for (int n = 0; n < 4; ++n) {
        int node = node0 + n;
        bool ok = node < N;
        bg[n] = ok ? row_ptr[node] : 0;
        en[n] = ok ? row_ptr[node + 1] : 0;
    }

    // self rows: groups 0..3 load nodes 0..3, groups 4..7 load zero row
    const int sn = g & 3;
    const int snode = node0 + sn;
    int ssrc = (g < 4 && snode < N) ? snode : N;
    unsigned int qs = hc[(size_t)ssrc * 8 + c];
    float a0[4], a1[4];
#pragma unroll
    for (int n = 0; n < 4; ++n) {
        a0[n] = (sn == n) ? bf2f_lo(qs) : 0.f;
        a1[n] = (sn == n) ? bf2f_hi(qs) : 0.f;
    }

    int T = 0;
#pragma unroll
    for (int n = 0; n < 4; ++n) T = max(T, (en[n] - bg[n] + 7) >> 3);

    if (T > 0) {
        int pos[4], rc[4];
#pragma unroll
        for (int n = 0; n < 4; ++n) {
            pos[n] = bg[n] + g;
            int cl = max(min(pos[n], en[n] - 1), 0);
            int ld = __builtin_nontemporal_load(&srcs[cl]);
            rc[n] = (pos[n] < en[n]) ? ld : N;
        }
        for (int it = 0; it < T; ++it) {
            unsigned int q0 = hc[(size_t)rc[0] * 8 + c];
            unsigned int q1 = hc[(size_t)rc[1] * 8 + c];
            unsigned int q2 = hc[(size_t)rc[2] * 8 + c];
            unsigned int q3 = hc[(size_t)rc[3] * 8 + c];
#pragma unroll
            for (int n = 0; n < 4; ++n) {
                pos[n] += 8;
                int cl = max(min(pos[n], en[n] - 1), 0);
                int ld = __builtin_nontemporal_load(&srcs[cl]);
                rc[n] = (pos[n] < en[n]) ? ld : N;
            }
            a0[0] += bf2f_lo(q0); a1[0] += bf2f_hi(q0);
            a0[1] += bf2f_lo(q1); a1[1] += bf2f_hi(q1);
            a0[2] += bf2f_lo(q2); a1[2] += bf2f_hi(q2);
            a0[3] += bf2f_lo(q3); a1[3] += bf2f_hi(q3);
        }
    }

    // reduce across the 8 edge-groups
#pragma unroll
    for (int n = 0; n < 4; ++n) {
        a0[n] += __shfl_xor(a0[n], 8, 64);  a1[n] += __shfl_xor(a1[n], 8, 64);
        a0[n] += __shfl_xor(a0[n], 16, 64); a1[n] += __shfl_xor(a1[n], 16, 64);
        a0[n] += __shfl_xor(a0[n], 32, 64); a1[n] += __shfl_xor(a1[n], 32, 64);
    }

    // groups 0..3 store node sn (static-index selection; rule #20)
    if (g < 4 && snode < N) {
        float r0 = (sn == 0) ? a0[0] : (sn == 1) ? a0[1] : (sn == 2) ? a0[2] : a0[3];
        float r1 = (sn == 0) ? a1[0] : (sn == 1) ? a1[1] : (sn == 2) ? a1[2] : a1[3];
        float dvd = dv[snode];
        int f = chunk * 16 + c * 2;
        float v0 = fmaxf(r0 * dvd + bias[f], 0.f);
        float v1 = fmaxf(r1 * dvd + bias[f + 1], 0.f);
        unsigned int o = (unsigned int)f2bf(v0) | ((unsigned int)f2bf(v1) << 16);
        *(unsigned int*)&agg1[(size_t)snode * 256 + f] = o;
    }
}

// ---- gemm2: h2s[node][64] = bf16(dv_node * (agg1 @ W2)), 16 nodes/block ---
__global__ __launch_bounds__(256) void gemm2_kernel(
    const uint4* __restrict__ A,            // agg1 rows = 32 uint4
    const unsigned short* __restrict__ W2t, // [64][256]
    const float* __restrict__ dv,
    unsigned short* __restrict__ h2s, int N) {
    __shared__ unsigned short As[16][264];
    const int tid = threadIdx.x;
    const int wave = tid >> 6, lane = tid & 63;
    const int node0 = blockIdx.x * 16;

    {   // stage 16 rows x 512 B; each thread 32 B
        int r = tid >> 4, q = tid & 15;
        int node = node0 + r;
        uint4 v0 = {0, 0, 0, 0}, v1 = v0;
        if (node < N) {
            v0 = A[(size_t)node * 32 + q * 2];
            v1 = A[(size_t)node * 32 + q * 2 + 1];
        }
        *(uint4*)&As[r][q * 16]     = v0;
        *(uint4*)&As[r][q * 16 + 8] = v1;
    }
    __syncthreads();

    const int quad = lane >> 4, l15 = lane & 15;
    f32x4 accd = {};
#pragma unroll
    for (int k0 = 0; k0 < 8; ++k0) {
        bf16x8 af = *(const bf16x8*)&As[l15][k0 * 32 + quad * 8];
        bf16x8 bf = *(const bf16x8*)&W2t[(size_t)(wave * 16 + l15) * 256 +
                                         k0 * 32 + quad * 8];
        accd = __builtin_amdgcn_mfma_f32_16x16x32_bf16(af, bf, accd, 0, 0, 0);
    }
#pragma unroll
    for (int r = 0; r < 4; ++r) {
        int node = node0 + quad * 4 + r;
        if (node < N)
            h2s[(size_t)node * 64 + wave * 16 + l15] =
                f2bf(accd[r] * dv[node]);
    }
}

// ---- out = log_softmax(dv_d * (A h2s) + b2), F=64 -------------------------
__global__ __launch_bounds__(256) void agg64_kernel(
    const uint4* __restrict__ h,  // h2s rows = 8 uint4 (64 bf16), N+1 rows
    const int* __restrict__ srcs, const int* __restrict__ row_ptr,
    const float* __restrict__ dv, const float* __restrict__ bias,
    float* __restrict__ out, int N) {
    const int node = blockIdx.x * 4 + (threadIdx.x >> 6);
    if (node >= N) return;
    const int lane = threadIdx.x & 63;
    const int g = lane >> 3;
    const int c = lane & 7;

    float acc[8] = {0.f, 0.f, 0.f, 0.f, 0.f, 0.f, 0.f, 0.f};
    {   // self: group 0 real row, others zero row
        int ss = (g == 0) ? node : N;
        uint4 q = h[(size_t)ss * 8 + c];
        acc8a(acc, q);
    }

    const int beg = row_ptr[node], end = row_ptr[node + 1];
    if (beg < end) {
        int p0 = beg + g, p1 = beg + 8 + g;
        int cl0 = max(min(p0, end - 1), 0), cl1 = max(min(p1, end - 1), 0);
        int l0 = __builtin_nontemporal_load(&srcs[cl0]);
        int l1 = __builtin_nontemporal_load(&srcs[cl1]);
        int r0 = (p0 < end) ? l0 : N;
        int r1 = (p1 < end) ? l1 : N;
        for (int e = beg; e < end; e += 16) {
            uint4 q0 = h[(size_t)r0 * 8 + c];
            uint4 q1 = h[(size_t)r1 * 8 + c];
            p0 += 16; p1 += 16;
            cl0 = max(min(p0, end - 1), 0); cl1 = max(min(p1, end - 1), 0);
            l0 = __builtin_nontemporal_load(&srcs[cl0]);
            l1 = __builtin_nontemporal_load(&srcs[cl1]);
            acc8a(acc, q0);
            acc8a(acc, q1);
            r0 = (p0 < end) ? l0 : N;
            r1 = (p1 < end) ? l1 : N;
        }
    }

#pragma unroll
    for (int k = 0; k < 8; ++k) {
        acc[k] += __shfl_xor(acc[k], 8, 64);
        acc[k] += __shfl_xor(acc[k], 16, 64);
        acc[k] += __shfl_xor(acc[k], 32, 64);
    }

    float dvd = dv[node];
    float4 b0 = *(const float4*)&bias[c * 8];
    float4 b1 = *(const float4*)&bias[c * 8 + 4];
    float v[8];
    v[0] = acc[0] * dvd + b0.x; v[1] = acc[1] * dvd + b0.y;
    v[2] = acc[2] * dvd + b0.z; v[3] = acc[3] * dvd + b0.w;
    v[4] = acc[4] * dvd + b1.x; v[5] = acc[5] * dvd + b1.y;
    v[6] = acc[6] * dvd + b1.z; v[7] = acc[7] * dvd + b1.w;

    float m = v[0];
#pragma unroll
    for (int k = 1; k < 8; ++k) m = fmaxf(m, v[k]);
    m = fmaxf(m, __shfl_xor(m, 1, 64));
    m = fmaxf(m, __shfl_xor(m, 2, 64));
    m = fmaxf(m, __shfl_xor(m, 4, 64));
    float s = 0.f;
#pragma unroll
    for (int k = 0; k < 8; ++k) s += expf(v[k] - m);
    s += __shfl_xor(s, 1, 64);
    s += __shfl_xor(s, 2, 64);
    s += __shfl_xor(s, 4, 64);
    float ls = m + logf(s);

    if (g == 0) {
        float4 o0, o1;
        o0.x = v[0] - ls; o0.y = v[1] - ls; o0.z = v[2] - ls; o0.w = v[3] - ls;
        o1.x = v[4] - ls; o1.y = v[5] - ls; o1.z = v[6] - ls; o1.w = v[7] - ls;
        *(float4*)&out[(size_t)node * 64 + c * 8] = o0;
        *(float4*)&out[(size_t)node * 64 + c * 8 + 4] = o1;
    }
}

extern "C" void kernel_launch(void* const* d_in, const int* in_sizes, int n_in,
                              void* d_out, int out_size, void* d_ws, size_t ws_size,
                              hipStream_t stream) {
    const float* x  = (const float*)d_in[0];
    const int*   ei = (const int*)d_in[1];
    const float* W1 = (const float*)d_in[2];
    const float* b1 = (const float*)d_in[3];
    const float* W2 = (const float*)d_in[4];
    const float* b2 = (const float*)d_in[5];
    float* out = (float*)d_out;

    const int N = in_sizes[0] / 256;  // 100000
    const int E = in_sizes[1] / 2;    // 1600000
    const int NP = 102400;
    const int NB = (N + 1023) / 1024;  // scan blocks (98)
    const int NBn = (N + 15) / 16;     // aggchunk node-blocks per chunk (6250)

    // Workspace layout (bytes; 16B-aligned segments). Total ~124 MB.
    char* ws = (char*)d_ws;
    int*   cnt     = (int*)ws;                 ws += (size_t)NP * 4;
    int*   fill    = (int*)ws;                 ws += (size_t)NP * 4;
    int*   row_ptr = (int*)ws;                 ws += (size_t)(NP + 4) * 4;
    int*   bsum    = (int*)ws;                 ws += (size_t)1024 * 4;
    int*   boffs   = (int*)ws;                 ws += (size_t)1024 * 4;
    int*   csr_src = (int*)ws;                 ws += (size_t)(E + 8) * 4;
    unsigned short* W1t = (unsigned short*)ws; ws += (size_t)256 * 256 * 2;
    unsigned short* W2t = (unsigned short*)ws; ws += (size_t)256 * 64 * 2;
    float* dv = (float*)ws;                    ws += (size_t)NP * 4;
    unsigned short* h1c  = (unsigned short*)ws; ws += (size_t)16 * (N + 1) * 16 * 2;
    unsigned short* agg1 = (unsigned short*)ws; ws += (size_t)N * 256 * 2;
    unsigned short* h2s  = (unsigned short*)ws; ws += (size_t)(N + 1) * 64 * 2;

    hipMemsetAsync(cnt, 0, (size_t)2 * NP * sizeof(int), stream);  // cnt+fill

    // CSR build
    deg_kernel<<<(E + 255) / 256, 256, 0, stream>>>(ei + E, E, cnt);
    dv_kernel<<<(N + 255) / 256, 256, 0, stream>>>(cnt, dv, h1c, h2s, N);
    scan_part1_kernel<<<NB, 256, 0, stream>>>(cnt, bsum, N);
    scan_part2_kernel<<<1, 1024, 0, stream>>>(bsum, boffs, NB, row_ptr, N);
    scan_part3_kernel<<<NB, 256, 0, stream>>>(cnt, boffs, row_ptr, N);
    scatter_kernel<<<(E + 255) / 256, 256, 0, stream>>>(
        ei, ei + E, row_ptr, fill, csr_src, E);

    // weight casts
    castw_kernel<<<(65536 + 16384 + 255) / 256, 256, 0, stream>>>(W1, W2, W1t, W2t);

    // h1c = chunk-major bf16(dv_row * (x @ W1))
    gemm1_kernel<<<(N + 127) / 128, 256, 0, stream>>>(x, W1t, dv, h1c, N);

    // agg1 = relu(dv_d * (A h1c) + b1), chunk-major sweeps (L2-resident)
    aggchunk_kernel<<<16 * NBn, 256, 0, stream>>>(
        (const unsigned int*)h1c, csr_src, row_ptr, dv, b1, agg1, N, NBn);

    // h2s = bf16(dv_node * (agg1 @ W2))
    gemm2_kernel<<<(N + 15) / 16, 256, 0, stream>>>(
        (const uint4*)agg1, W2t, dv, h2s, N);

    // out = log_softmax(dv_d * (A h2s) + b2)
    agg64_kernel<<<(N + 3) / 4, 256, 0, stream>>>(
        (const uint4*)h2s, csr_src, row_ptr, dv, b2, out, N);
}

// Round 3
// 578.514 us; speedup vs baseline: 1.4383x; 1.4383x over previous
//
#include <hip/hip_runtime.h>
#include <math.h>

// ---------------------------------------------------------------------------
// GCN 2-layer forward on MI355X. Round 11: revert r10's chunking (XCD-L2
// replication made FETCH 387 MB and 32B-gathers made it VALU-bound at 220+
// us); back to the r9 structure, plus the one verified-good r10 idea:
//   * rows pre-scaled by dv_src (gemm1 epilog) -> edge recs are src-only
//     int32 (6.4 MB, was int2 12.8 MB). No weights in the gather loops.
//   * self-loop = weight-1 add of own (pre-scaled) row; tail & off-half
//     slots gather a zeroed pad row N. dv_dst applied once per node.
//   * dv computed inside scan_part3 (free); h2s pre-scaled by dv_node in
//     aggfused phase-2 epilog (free).
//   * nontemporal hints on all stream-once traffic (x, ei, rank, srcs, out)
//     to protect L2/L3 residency of the gather tables (h1s, h2s).
// ---------------------------------------------------------------------------

typedef __attribute__((ext_vector_type(8))) short bf16x8;
typedef __attribute__((ext_vector_type(4))) float f32x4;

__device__ inline unsigned short f2bf(float f) {
    union { float f; unsigned int u; } v; v.f = f;
    unsigned int r = v.u + 0x7fffu + ((v.u >> 16) & 1u);  // RNE
    return (unsigned short)(r >> 16);
}
__device__ inline float bf2f_lo(unsigned int u) {
    union { unsigned int u; float f; } v; v.u = u << 16; return v.f;
}
__device__ inline float bf2f_hi(unsigned int u) {
    union { unsigned int u; float f; } v; v.u = u & 0xffff0000u; return v.f;
}

// unpack uint4 (8 bf16) and ADD into acc[8] (rows are pre-scaled; no weight)
__device__ inline void acc8a(float* acc, uint4 q) {
    acc[0] += bf2f_lo(q.x); acc[1] += bf2f_hi(q.x);
    acc[2] += bf2f_lo(q.y); acc[3] += bf2f_hi(q.y);
    acc[4] += bf2f_lo(q.z); acc[5] += bf2f_hi(q.z);
    acc[6] += bf2f_lo(q.w); acc[7] += bf2f_hi(q.w);
}

// ---------------- CSR build ----------------
__global__ __launch_bounds__(256) void deg_rank_kernel(
    const int* __restrict__ dst, int E, int* __restrict__ cnt,
    int* __restrict__ rank) {
    int e = blockIdx.x * blockDim.x + threadIdx.x;
    if (e < E) {
        int d = __builtin_nontemporal_load(&dst[e]);
        int r = atomicAdd(&cnt[d], 1);
        __builtin_nontemporal_store(r, &rank[e]);
    }
}

__global__ __launch_bounds__(256) void scan_part1_kernel(
    const int* __restrict__ cnt, int* __restrict__ bsum, int N) {
    __shared__ int s[256];
    const int tid = threadIdx.x;
    int base = blockIdx.x * 1024 + tid * 4;
    int v = 0;
#pragma unroll
    for (int j = 0; j < 4; ++j)
        if (base + j < N) v += cnt[base + j];
    s[tid] = v;
    __syncthreads();
    for (int off = 128; off > 0; off >>= 1) {
        if (tid < off) s[tid] += s[tid + off];
        __syncthreads();
    }
    if (tid == 0) bsum[blockIdx.x] = s[0];
}

__global__ __launch_bounds__(1024) void scan_part2_kernel(
    const int* __restrict__ bsum, int* __restrict__ boffs, int NB,
    int* __restrict__ row_ptr, int N) {
    __shared__ int s[1024];
    const int tid = threadIdx.x;
    int v = (tid < NB) ? bsum[tid] : 0;
    s[tid] = v;
    __syncthreads();
    for (int off = 1; off < 1024; off <<= 1) {
        int t = (tid >= off) ? s[tid - off] : 0;
        __syncthreads();
        if (tid >= off) s[tid] += t;
        __syncthreads();
    }
    if (tid < NB) boffs[tid] = s[tid] - v;  // exclusive
    if (tid == 1023) row_ptr[N] = s[1023];  // grand total
}

// also emits dv[n] = rsqrt(deg_incl_self) — free fusion (cnt already here)
__global__ __launch_bounds__(256) void scan_part3_kernel(
    const int* __restrict__ cnt, const int* __restrict__ boffs,
    int* __restrict__ row_ptr, float* __restrict__ dv, int N) {
    __shared__ int s[256];
    const int tid = threadIdx.x;
    int base = blockIdx.x * 1024 + tid * 4;
    int c[4];
    int v = 0;
#pragma unroll
    for (int j = 0; j < 4; ++j) {
        c[j] = (base + j < N) ? cnt[base + j] : 0;
        v += c[j];
    }
    s[tid] = v;
    __syncthreads();
    for (int off = 1; off < 256; off <<= 1) {
        int t = (tid >= off) ? s[tid - off] : 0;
        __syncthreads();
        if (tid >= off) s[tid] += t;
        __syncthreads();
    }
    int run = boffs[blockIdx.x] + s[tid] - v;
#pragma unroll
    for (int j = 0; j < 4; ++j) {
        if (base + j < N) {
            row_ptr[base + j] = run;
            dv[base + j] = rsqrtf((float)c[j] + 1.0f);
            run += c[j];
        }
    }
}

// Atomic-free scatter: csr_src[row_ptr[d] + rank] = s. Src-only payload.
__global__ __launch_bounds__(256) void scatter_kernel(
    const int* __restrict__ src, const int* __restrict__ dst,
    const int* __restrict__ rank, const int* __restrict__ row_ptr,
    int* __restrict__ csr_src, int E) {
    int e = blockIdx.x * blockDim.x + threadIdx.x;
    if (e >= E) return;
    int d = __builtin_nontemporal_load(&dst[e]);
    int s = __builtin_nontemporal_load(&src[e]);
    int r = __builtin_nontemporal_load(&rank[e]);
    csr_src[row_ptr[d] + r] = s;
}

// ------ weight cast+transpose + pad-row zeroing ----------------------------
__global__ __launch_bounds__(256) void castw_kernel(
    const float* __restrict__ W1, const float* __restrict__ W2,
    unsigned short* __restrict__ W1t, unsigned short* __restrict__ W2t,
    unsigned short* __restrict__ h1s, unsigned short* __restrict__ h2s,
    int N) {
    int i = blockIdx.x * 256 + threadIdx.x;
    if (i < 65536) {  // W1: 256x256
        int n = i >> 8, k = i & 255;
        W1t[i] = f2bf(W1[(size_t)k * 256 + n]);
    } else if (i < 65536 + 16384) {  // W2: 256x64 -> W2t[64][256]
        int j = i - 65536;
        int n = j >> 8, k = j & 255;
        W2t[j] = f2bf(W2[(size_t)k * 64 + n]);
    } else {  // block 320: zero pad rows (workspace may be re-poisoned)
        int t = i - (65536 + 16384);
        h1s[(size_t)N * 256 + t] = 0;
        if (t < 64) h2s[(size_t)N * 64 + t] = 0;
    }
}

// ---- GEMM1: h1s[row][256] = bf16(dv_row * (x @ W1)), MFMA -----------------
// 128(M) x 256(N) tile, BK=32. Wave w owns cols [64w, 64w+64).
__global__ __launch_bounds__(256) void gemm1_kernel(
    const float* __restrict__ A, const unsigned short* __restrict__ Bt,
    const float* __restrict__ dv, unsigned short* __restrict__ C, int M) {
    __shared__ unsigned short As[128][32];   // 8 KB
    __shared__ unsigned short Bs[256][32];   // 16 KB

    const int tid = threadIdx.x;
    const int wave = tid >> 6, lane = tid & 63;
    const int quad = lane >> 4, l15 = lane & 15;
    const int m0 = blockIdx.x * 128;

    f32x4 acc[8][4] = {};

    const int arow = tid >> 1;          // 0..127
    const int akk  = (tid & 1) << 4;    // 0 or 16
    const int gr = m0 + arow;

    for (int k0 = 0; k0 < 256; k0 += 32) {
        f32x4 a0 = {0.f, 0.f, 0.f, 0.f}, a1 = a0, a2 = a0, a3 = a0;
        if (gr < M) {
            const f32x4* ap = (const f32x4*)&A[(size_t)gr * 256 + k0 + akk];
            a0 = __builtin_nontemporal_load(&ap[0]);
            a1 = __builtin_nontemporal_load(&ap[1]);
            a2 = __builtin_nontemporal_load(&ap[2]);
            a3 = __builtin_nontemporal_load(&ap[3]);
        }
        bf16x8 av0, av1;
        av0[0] = (short)f2bf(a0[0]); av0[1] = (short)f2bf(a0[1]);
        av0[2] = (short)f2bf(a0[2]); av0[3] = (short)f2bf(a0[3]);
        av0[4] = (short)f2bf(a1[0]); av0[5] = (short)f2bf(a1[1]);
        av0[6] = (short)f2bf(a1[2]); av0[7] = (short)f2bf(a1[3]);
        av1[0] = (short)f2bf(a2[0]); av1[1] = (short)f2bf(a2[1]);
        av1[2] = (short)f2bf(a2[2]); av1[3] = (short)f2bf(a2[3]);
        av1[4] = (short)f2bf(a3[0]); av1[5] = (short)f2bf(a3[1]);
        av1[6] = (short)f2bf(a3[2]); av1[7] = (short)f2bf(a3[3]);
        *(bf16x8*)&As[arow][akk]     = av0;
        *(bf16x8*)&As[arow][akk + 8] = av1;

        const unsigned short* bsrc = &Bt[(size_t)tid * 256 + k0];
        *(bf16x8*)&Bs[tid][0]  = *(const bf16x8*)&bsrc[0];
        *(bf16x8*)&Bs[tid][8]  = *(const bf16x8*)&bsrc[8];
        *(bf16x8*)&Bs[tid][16] = *(const bf16x8*)&bsrc[16];
        *(bf16x8*)&Bs[tid][24] = *(const bf16x8*)&bsrc[24];
        __syncthreads();

        bf16x8 bfv[4];
#pragma unroll
        for (int nt = 0; nt < 4; ++nt)
            bfv[nt] = *(const bf16x8*)&Bs[wave * 64 + nt * 16 + l15][quad * 8];
#pragma unroll
        for (int mt = 0; mt < 8; ++mt) {
            bf16x8 af = *(const bf16x8*)&As[mt * 16 + l15][quad * 8];
#pragma unroll
            for (int nt = 0; nt < 4; ++nt)
                acc[mt][nt] = __builtin_amdgcn_mfma_f32_16x16x32_bf16(
                    af, bfv[nt], acc[mt][nt], 0, 0, 0);
        }
        __syncthreads();
    }

#pragma unroll
    for (int mt = 0; mt < 8; ++mt) {
#pragma unroll
        for (int r = 0; r < 4; ++r) {
            int grow = m0 + mt * 16 + quad * 4 + r;
            if (grow < M) {
                float sc = dv[grow];
#pragma unroll
                for (int nt = 0; nt < 4; ++nt)
                    C[(size_t)grow * 256 + wave * 64 + nt * 16 + l15] =
                        f2bf(acc[mt][nt][r] * sc);
            }
        }
    }
}

// ---- FUSED: h2s = bf16( dv_n * (relu(dv_n*(A h1s) + b1) @ W2) ) -----------
// Phase 1 (per wave, 4 nodes): src-only gather, clamped stride-8 loop with
// next-iter src prefetch; rows pre-scaled so no weights. Phase 2: MFMA.
__global__ __launch_bounds__(256) void aggfused_kernel(
    const uint4* __restrict__ h,  // h1s rows = 32 uint4 (256 bf16), N+1 rows
    const int* __restrict__ srcs,
    const int* __restrict__ row_ptr, const float* __restrict__ dv,
    const float* __restrict__ bias, const unsigned short* __restrict__ W2t,
    unsigned short* __restrict__ h2s, int N) {
    __shared__ unsigned short As[16][264];  // +8 bf16 pad

    const int tid = threadIdx.x;
    const int wave = tid >> 6, lane = tid & 63;
    const int half = lane >> 5;
    const int c = lane & 31;
    const int node0 = blockIdx.x * 16;

    for (int i = 0; i < 4; ++i) {
        const int local = wave * 4 + i;
        const int node = node0 + local;
        float acc[8] = {0.f, 0.f, 0.f, 0.f, 0.f, 0.f, 0.f, 0.f};
        float dvd = 0.f;
        if (node < N) {
            dvd = dv[node];
            // self row: half 0 gathers the real row (weight 1), half 1 zeros
            uint4 qs = h[(size_t)(half == 0 ? node : N) * 32 + c];
            const int beg = row_ptr[node], end = row_ptr[node + 1];
            acc8a(acc, qs);
            if (beg < end) {
                int p0 = beg + half, p1 = beg + 2 + half,
                    p2 = beg + 4 + half, p3 = beg + 6 + half;
                // srcs has +16 slop ints; loads past end are selected to N
                int r0 = (p0 < end) ? __builtin_nontemporal_load(&srcs[p0]) : N;
                int r1 = (p1 < end) ? __builtin_nontemporal_load(&srcs[p1]) : N;
                int r2 = (p2 < end) ? __builtin_nontemporal_load(&srcs[p2]) : N;
                int r3 = (p3 < end) ? __builtin_nontemporal_load(&srcs[p3]) : N;
                for (int e = beg; e < end; e += 8) {
                    uint4 q0 = h[(size_t)r0 * 32 + c];
                    uint4 q1 = h[(size_t)r1 * 32 + c];
                    uint4 q2 = h[(size_t)r2 * 32 + c];
                    uint4 q3 = h[(size_t)r3 * 32 + c];
                    p0 += 8; p1 += 8; p2 += 8; p3 += 8;
                    int n0 = (p0 < end) ? __builtin_nontemporal_load(&srcs[p0]) : N;
                    int n1 = (p1 < end) ? __builtin_nontemporal_load(&srcs[p1]) : N;
                    int n2 = (p2 < end) ? __builtin_nontemporal_load(&srcs[p2]) : N;
                    int n3 = (p3 < end) ? __builtin_nontemporal_load(&srcs[p3]) : N;
                    acc8a(acc, q0);
                    acc8a(acc, q1);
                    acc8a(acc, q2);
                    acc8a(acc, q3);
                    r0 = n0; r1 = n1; r2 = n2; r3 = n3;
                }
            }
        }
#pragma unroll
        for (int k = 0; k < 8; ++k) acc[k] += __shfl_xor(acc[k], 32, 64);

        if (half == 0) {
            float4 b0 = *(const float4*)&bias[c * 8];
            float4 b1 = *(const float4*)&bias[c * 8 + 4];
            unsigned int o0 = f2bf(fmaxf(acc[0] * dvd + b0.x, 0.f));
            unsigned int o1 = f2bf(fmaxf(acc[1] * dvd + b0.y, 0.f));
            unsigned int o2 = f2bf(fmaxf(acc[2] * dvd + b0.z, 0.f));
            unsigned int o3 = f2bf(fmaxf(acc[3] * dvd + b0.w, 0.f));
            unsigned int o4 = f2bf(fmaxf(acc[4] * dvd + b1.x, 0.f));
            unsigned int o5 = f2bf(fmaxf(acc[5] * dvd + b1.y, 0.f));
            unsigned int o6 = f2bf(fmaxf(acc[6] * dvd + b1.z, 0.f));
            unsigned int o7 = f2bf(fmaxf(acc[7] * dvd + b1.w, 0.f));
            uint4 ov;
            ov.x = o0 | (o1 << 16);
            ov.y = o2 | (o3 << 16);
            ov.z = o4 | (o5 << 16);
            ov.w = o6 | (o7 << 16);
            *(uint4*)&As[local][c * 8] = ov;
        }
    }
    __syncthreads();

    // Phase 2: D[16 nodes][64 cols] = As[16][256] @ W2t^T; pre-scale by dv.
    const int quad = lane >> 4, l15 = lane & 15;
    f32x4 accd = {};
#pragma unroll
    for (int k0 = 0; k0 < 8; ++k0) {
        bf16x8 af = *(const bf16x8*)&As[l15][k0 * 32 + quad * 8];
        bf16x8 bf = *(const bf16x8*)&W2t[(size_t)(wave * 16 + l15) * 256 +
                                         k0 * 32 + quad * 8];
        accd = __builtin_amdgcn_mfma_f32_16x16x32_bf16(af, bf, accd, 0, 0, 0);
    }
#pragma unroll
    for (int r = 0; r < 4; ++r) {
        int node = node0 + quad * 4 + r;
        if (node < N)
            h2s[(size_t)node * 64 + wave * 16 + l15] =
                f2bf(accd[r] * dv[node]);
    }
}

// ---- out = log_softmax(dv_d * (A h2s) + b2), F=64 -------------------------
__global__ __launch_bounds__(256) void agg64_kernel(
    const uint4* __restrict__ h,  // h2s rows = 8 uint4 (64 bf16), N+1 rows
    const int* __restrict__ srcs, const int* __restrict__ row_ptr,
    const float* __restrict__ dv, const float* __restrict__ bias,
    float* __restrict__ out, int N) {
    const int node = blockIdx.x * 4 + (threadIdx.x >> 6);
    if (node >= N) return;
    const int lane = threadIdx.x & 63;
    const int g = lane >> 3;
    const int c = lane & 7;

    float acc[8] = {0.f, 0.f, 0.f, 0.f, 0.f, 0.f, 0.f, 0.f};
    {   // self: group 0 real row (weight 1), others zero row
        uint4 q = h[(size_t)(g == 0 ? node : N) * 8 + c];
        acc8a(acc, q);
    }

    const int beg = row_ptr[node], end = row_ptr[node + 1];
    if (beg < end) {
        int p0 = beg + g, p1 = beg + 8 + g;
        int r0 = (p0 < end) ? __builtin_nontemporal_load(&srcs[p0]) : N;
        int r1 = (p1 < end) ? __builtin_nontemporal_load(&srcs[p1]) : N;
        for (int e = beg; e < end; e += 16) {
            uint4 q0 = h[(size_t)r0 * 8 + c];
            uint4 q1 = h[(size_t)r1 * 8 + c];
            p0 += 16; p1 += 16;
            int n0 = (p0 < end) ? __builtin_nontemporal_load(&srcs[p0]) : N;
            int n1 = (p1 < end) ? __builtin_nontemporal_load(&srcs[p1]) : N;
            acc8a(acc, q0);
            acc8a(acc, q1);
            r0 = n0; r1 = n1;
        }
    }

#pragma unroll
    for (int k = 0; k < 8; ++k) {
        acc[k] += __shfl_xor(acc[k], 8, 64);
        acc[k] += __shfl_xor(acc[k], 16, 64);
        acc[k] += __shfl_xor(acc[k], 32, 64);
    }

    float dvd = dv[node];
    float4 b0 = *(const float4*)&bias[c * 8];
    float4 b1 = *(const float4*)&bias[c * 8 + 4];
    float v[8];
    v[0] = acc[0] * dvd + b0.x; v[1] = acc[1] * dvd + b0.y;
    v[2] = acc[2] * dvd + b0.z; v[3] = acc[3] * dvd + b0.w;
    v[4] = acc[4] * dvd + b1.x; v[5] = acc[5] * dvd + b1.y;
    v[6] = acc[6] * dvd + b1.z; v[7] = acc[7] * dvd + b1.w;

    float m = v[0];
#pragma unroll
    for (int k = 1; k < 8; ++k) m = fmaxf(m, v[k]);
    m = fmaxf(m, __shfl_xor(m, 1, 64));
    m = fmaxf(m, __shfl_xor(m, 2, 64));
    m = fmaxf(m, __shfl_xor(m, 4, 64));
    float s = 0.f;
#pragma unroll
    for (int k = 0; k < 8; ++k) s += expf(v[k] - m);
    s += __shfl_xor(s, 1, 64);
    s += __shfl_xor(s, 2, 64);
    s += __shfl_xor(s, 4, 64);
    float ls = m + logf(s);

    if (g == 0) {
        f32x4 o0 = {v[0] - ls, v[1] - ls, v[2] - ls, v[3] - ls};
        f32x4 o1 = {v[4] - ls, v[5] - ls, v[6] - ls, v[7] - ls};
        __builtin_nontemporal_store(o0, (f32x4*)&out[(size_t)node * 64 + c * 8]);
        __builtin_nontemporal_store(o1, (f32x4*)&out[(size_t)node * 64 + c * 8 + 4]);
    }
}

extern "C" void kernel_launch(void* const* d_in, const int* in_sizes, int n_in,
                              void* d_out, int out_size, void* d_ws, size_t ws_size,
                              hipStream_t stream) {
    const float* x  = (const float*)d_in[0];
    const int*   ei = (const int*)d_in[1];
    const float* W1 = (const float*)d_in[2];
    const float* b1 = (const float*)d_in[3];
    const float* W2 = (const float*)d_in[4];
    const float* b2 = (const float*)d_in[5];
    float* out = (float*)d_out;

    const int N = in_sizes[0] / 256;  // 100000
    const int E = in_sizes[1] / 2;    // 1600000
    const int NP = 102400;
    const int NB = (N + 1023) / 1024;  // scan blocks (98)

    // Workspace layout (bytes; 16B-aligned segments). Total ~78 MB.
    char* ws = (char*)d_ws;
    int*   cnt     = (int*)ws;                 ws += (size_t)NP * 4;
    int*   rank    = (int*)ws;                 ws += (size_t)E * 4;
    int*   row_ptr = (int*)ws;                 ws += (size_t)(NP + 4) * 4;
    int*   bsum    = (int*)ws;                 ws += (size_t)1024 * 4;
    int*   boffs   = (int*)ws;                 ws += (size_t)1024 * 4;
    int*   csr_src = (int*)ws;                 ws += (size_t)(E + 16) * 4;
    unsigned short* W1t = (unsigned short*)ws; ws += (size_t)256 * 256 * 2;
    unsigned short* W2t = (unsigned short*)ws; ws += (size_t)256 * 64 * 2;
    float* dv = (float*)ws;                    ws += (size_t)NP * 4;
    unsigned short* h1s = (unsigned short*)ws; ws += (size_t)(N + 1) * 256 * 2;
    unsigned short* h2s = (unsigned short*)ws; ws += (size_t)(N + 1) * 64 * 2;

    hipMemsetAsync(cnt, 0, (size_t)N * sizeof(int), stream);

    // CSR build (one atomic pass; scatter is atomic-free)
    deg_rank_kernel<<<(E + 255) / 256, 256, 0, stream>>>(ei + E, E, cnt, rank);
    scan_part1_kernel<<<NB, 256, 0, stream>>>(cnt, bsum, N);
    scan_part2_kernel<<<1, 1024, 0, stream>>>(bsum, boffs, NB, row_ptr, N);
    scan_part3_kernel<<<NB, 256, 0, stream>>>(cnt, boffs, row_ptr, dv, N);
    scatter_kernel<<<(E + 255) / 256, 256, 0, stream>>>(
        ei, ei + E, rank, row_ptr, csr_src, E);

    // weight casts + pad-row zeroing (321st block)
    castw_kernel<<<321, 256, 0, stream>>>(W1, W2, W1t, W2t, h1s, h2s, N);

    // h1s = bf16(dv_row * (x @ W1))
    gemm1_kernel<<<(N + 127) / 128, 256, 0, stream>>>(x, W1t, dv, h1s, N);

    // h2s = bf16( dv_n * (relu(dv_n * (A h1s) + b1) @ W2) )  [fused]
    aggfused_kernel<<<(N + 15) / 16, 256, 0, stream>>>(
        (const uint4*)h1s, csr_src, row_ptr, dv, b1, W2t, h2s, N);

    // out = log_softmax(dv_d * (A h2s) + b2)
    agg64_kernel<<<(N + 3) / 4, 256, 0, stream>>>(
        (const uint4*)h2s, csr_src, row_ptr, dv, b2, out, N);
}

// Round 4
// 548.647 us; speedup vs baseline: 1.5166x; 1.0544x over previous
//
#include <hip/hip_runtime.h>
#include <math.h>

// ---------------------------------------------------------------------------
// GCN 2-layer forward on MI355X. Round 12: consolidation.
//   r11 post-mortem: nontemporal hints on re-read lines (srcs stream read
//   8-16x per 64B line by the same wave) evicted them early -> extra HBM
//   fetch; dvd live across the gather loop cost 4 VGPR -> occupancy 70->61%.
//   This round: r11 structure with ALL NT hints removed, dv load moved out
//   of the hot loop. Keep the verified-good byte cuts: src-only int32 CSR
//   (6.4 MB), dv fused into scan_part3, rows pre-scaled by dv_src (no
//   weights anywhere), pad-row N for tail/self handling.
// ---------------------------------------------------------------------------

typedef __attribute__((ext_vector_type(8))) short bf16x8;
typedef __attribute__((ext_vector_type(4))) float f32x4;

__device__ inline unsigned short f2bf(float f) {
    union { float f; unsigned int u; } v; v.f = f;
    unsigned int r = v.u + 0x7fffu + ((v.u >> 16) & 1u);  // RNE
    return (unsigned short)(r >> 16);
}
__device__ inline float bf2f_lo(unsigned int u) {
    union { unsigned int u; float f; } v; v.u = u << 16; return v.f;
}
__device__ inline float bf2f_hi(unsigned int u) {
    union { unsigned int u; float f; } v; v.u = u & 0xffff0000u; return v.f;
}

// unpack uint4 (8 bf16) and ADD into acc[8] (rows are pre-scaled; no weight)
__device__ inline void acc8a(float* acc, uint4 q) {
    acc[0] += bf2f_lo(q.x); acc[1] += bf2f_hi(q.x);
    acc[2] += bf2f_lo(q.y); acc[3] += bf2f_hi(q.y);
    acc[4] += bf2f_lo(q.z); acc[5] += bf2f_hi(q.z);
    acc[6] += bf2f_lo(q.w); acc[7] += bf2f_hi(q.w);
}

// ---------------- CSR build ----------------
__global__ __launch_bounds__(256) void deg_rank_kernel(
    const int* __restrict__ dst, int E, int* __restrict__ cnt,
    int* __restrict__ rank) {
    int e = blockIdx.x * blockDim.x + threadIdx.x;
    if (e < E) rank[e] = atomicAdd(&cnt[dst[e]], 1);
}

__global__ __launch_bounds__(256) void scan_part1_kernel(
    const int* __restrict__ cnt, int* __restrict__ bsum, int N) {
    __shared__ int s[256];
    const int tid = threadIdx.x;
    int base = blockIdx.x * 1024 + tid * 4;
    int v = 0;
#pragma unroll
    for (int j = 0; j < 4; ++j)
        if (base + j < N) v += cnt[base + j];
    s[tid] = v;
    __syncthreads();
    for (int off = 128; off > 0; off >>= 1) {
        if (tid < off) s[tid] += s[tid + off];
        __syncthreads();
    }
    if (tid == 0) bsum[blockIdx.x] = s[0];
}

__global__ __launch_bounds__(1024) void scan_part2_kernel(
    const int* __restrict__ bsum, int* __restrict__ boffs, int NB,
    int* __restrict__ row_ptr, int N) {
    __shared__ int s[1024];
    const int tid = threadIdx.x;
    int v = (tid < NB) ? bsum[tid] : 0;
    s[tid] = v;
    __syncthreads();
    for (int off = 1; off < 1024; off <<= 1) {
        int t = (tid >= off) ? s[tid - off] : 0;
        __syncthreads();
        if (tid >= off) s[tid] += t;
        __syncthreads();
    }
    if (tid < NB) boffs[tid] = s[tid] - v;  // exclusive
    if (tid == 1023) row_ptr[N] = s[1023];  // grand total
}

// also emits dv[n] = rsqrt(deg_incl_self) — free fusion (cnt already here)
__global__ __launch_bounds__(256) void scan_part3_kernel(
    const int* __restrict__ cnt, const int* __restrict__ boffs,
    int* __restrict__ row_ptr, float* __restrict__ dv, int N) {
    __shared__ int s[256];
    const int tid = threadIdx.x;
    int base = blockIdx.x * 1024 + tid * 4;
    int c[4];
    int v = 0;
#pragma unroll
    for (int j = 0; j < 4; ++j) {
        c[j] = (base + j < N) ? cnt[base + j] : 0;
        v += c[j];
    }
    s[tid] = v;
    __syncthreads();
    for (int off = 1; off < 256; off <<= 1) {
        int t = (tid >= off) ? s[tid - off] : 0;
        __syncthreads();
        if (tid >= off) s[tid] += t;
        __syncthreads();
    }
    int run = boffs[blockIdx.x] + s[tid] - v;
#pragma unroll
    for (int j = 0; j < 4; ++j) {
        if (base + j < N) {
            row_ptr[base + j] = run;
            dv[base + j] = rsqrtf((float)c[j] + 1.0f);
            run += c[j];
        }
    }
}

// Atomic-free scatter: csr_src[row_ptr[d] + rank] = s. Src-only payload.
__global__ __launch_bounds__(256) void scatter_kernel(
    const int* __restrict__ src, const int* __restrict__ dst,
    const int* __restrict__ rank, const int* __restrict__ row_ptr,
    int* __restrict__ csr_src, int E) {
    int e = blockIdx.x * blockDim.x + threadIdx.x;
    if (e >= E) return;
    int d = dst[e];
    csr_src[row_ptr[d] + rank[e]] = src[e];
}

// ------ weight cast+transpose + pad-row zeroing ----------------------------
__global__ __launch_bounds__(256) void castw_kernel(
    const float* __restrict__ W1, const float* __restrict__ W2,
    unsigned short* __restrict__ W1t, unsigned short* __restrict__ W2t,
    unsigned short* __restrict__ h1s, unsigned short* __restrict__ h2s,
    int N) {
    int i = blockIdx.x * 256 + threadIdx.x;
    if (i < 65536) {  // W1: 256x256
        int n = i >> 8, k = i & 255;
        W1t[i] = f2bf(W1[(size_t)k * 256 + n]);
    } else if (i < 65536 + 16384) {  // W2: 256x64 -> W2t[64][256]
        int j = i - 65536;
        int n = j >> 8, k = j & 255;
        W2t[j] = f2bf(W2[(size_t)k * 64 + n]);
    } else {  // block 320: zero pad rows (workspace may be re-poisoned)
        int t = i - (65536 + 16384);
        h1s[(size_t)N * 256 + t] = 0;
        if (t < 64) h2s[(size_t)N * 64 + t] = 0;
    }
}

// ---- GEMM1: h1s[row][256] = bf16(dv_row * (x @ W1)), MFMA -----------------
// 128(M) x 256(N) tile, BK=32. Wave w owns cols [64w, 64w+64).
__global__ __launch_bounds__(256) void gemm1_kernel(
    const float* __restrict__ A, const unsigned short* __restrict__ Bt,
    const float* __restrict__ dv, unsigned short* __restrict__ C, int M) {
    __shared__ unsigned short As[128][32];   // 8 KB
    __shared__ unsigned short Bs[256][32];   // 16 KB

    const int tid = threadIdx.x;
    const int wave = tid >> 6, lane = tid & 63;
    const int quad = lane >> 4, l15 = lane & 15;
    const int m0 = blockIdx.x * 128;

    f32x4 acc[8][4] = {};

    const int arow = tid >> 1;          // 0..127
    const int akk  = (tid & 1) << 4;    // 0 or 16
    const int gr = m0 + arow;

    for (int k0 = 0; k0 < 256; k0 += 32) {
        float4 a0 = make_float4(0.f,0.f,0.f,0.f), a1 = a0, a2 = a0, a3 = a0;
        if (gr < M) {
            const float* ap = &A[(size_t)gr * 256 + k0 + akk];
            a0 = *(const float4*)&ap[0];
            a1 = *(const float4*)&ap[4];
            a2 = *(const float4*)&ap[8];
            a3 = *(const float4*)&ap[12];
        }
        bf16x8 av0, av1;
        av0[0] = (short)f2bf(a0.x); av0[1] = (short)f2bf(a0.y);
        av0[2] = (short)f2bf(a0.z); av0[3] = (short)f2bf(a0.w);
        av0[4] = (short)f2bf(a1.x); av0[5] = (short)f2bf(a1.y);
        av0[6] = (short)f2bf(a1.z); av0[7] = (short)f2bf(a1.w);
        av1[0] = (short)f2bf(a2.x); av1[1] = (short)f2bf(a2.y);
        av1[2] = (short)f2bf(a2.z); av1[3] = (short)f2bf(a2.w);
        av1[4] = (short)f2bf(a3.x); av1[5] = (short)f2bf(a3.y);
        av1[6] = (short)f2bf(a3.z); av1[7] = (short)f2bf(a3.w);
        *(bf16x8*)&As[arow][akk]     = av0;
        *(bf16x8*)&As[arow][akk + 8] = av1;

        const unsigned short* bsrc = &Bt[(size_t)tid * 256 + k0];
        *(bf16x8*)&Bs[tid][0]  = *(const bf16x8*)&bsrc[0];
        *(bf16x8*)&Bs[tid][8]  = *(const bf16x8*)&bsrc[8];
        *(bf16x8*)&Bs[tid][16] = *(const bf16x8*)&bsrc[16];
        *(bf16x8*)&Bs[tid][24] = *(const bf16x8*)&bsrc[24];
        __syncthreads();

        bf16x8 bfv[4];
#pragma unroll
        for (int nt = 0; nt < 4; ++nt)
            bfv[nt] = *(const bf16x8*)&Bs[wave * 64 + nt * 16 + l15][quad * 8];
#pragma unroll
        for (int mt = 0; mt < 8; ++mt) {
            bf16x8 af = *(const bf16x8*)&As[mt * 16 + l15][quad * 8];
#pragma unroll
            for (int nt = 0; nt < 4; ++nt)
                acc[mt][nt] = __builtin_amdgcn_mfma_f32_16x16x32_bf16(
                    af, bfv[nt], acc[mt][nt], 0, 0, 0);
        }
        __syncthreads();
    }

#pragma unroll
    for (int mt = 0; mt < 8; ++mt) {
#pragma unroll
        for (int r = 0; r < 4; ++r) {
            int grow = m0 + mt * 16 + quad * 4 + r;
            if (grow < M) {
                float sc = dv[grow];
#pragma unroll
                for (int nt = 0; nt < 4; ++nt)
                    C[(size_t)grow * 256 + wave * 64 + nt * 16 + l15] =
                        f2bf(acc[mt][nt][r] * sc);
            }
        }
    }
}

// ---- FUSED: h2s = bf16( dv_n * (relu(dv_n*(A h1s) + b1) @ W2) ) -----------
// Phase 1 (per wave, 4 nodes): src-only gather, clamped stride-8 loop with
// next-iter src prefetch; rows pre-scaled so no weights. Phase 2: MFMA.
__global__ __launch_bounds__(256) void aggfused_kernel(
    const uint4* __restrict__ h,  // h1s rows = 32 uint4 (256 bf16), N+1 rows
    const int* __restrict__ srcs,
    const int* __restrict__ row_ptr, const float* __restrict__ dv,
    const float* __restrict__ bias, const unsigned short* __restrict__ W2t,
    unsigned short* __restrict__ h2s, int N) {
    __shared__ unsigned short As[16][264];  // +8 bf16 pad

    const int tid = threadIdx.x;
    const int wave = tid >> 6, lane = tid & 63;
    const int half = lane >> 5;
    const int c = lane & 31;
    const int node0 = blockIdx.x * 16;

    for (int i = 0; i < 4; ++i) {
        const int local = wave * 4 + i;
        const int node = node0 + local;
        float acc[8] = {0.f, 0.f, 0.f, 0.f, 0.f, 0.f, 0.f, 0.f};
        if (node < N) {
            // self row: half 0 gathers the real row (weight 1), half 1 zeros
            uint4 qs = h[(size_t)(half == 0 ? node : N) * 32 + c];
            const int beg = row_ptr[node], end = row_ptr[node + 1];
            acc8a(acc, qs);
            if (beg < end) {
                int p0 = beg + half, p1 = beg + 2 + half,
                    p2 = beg + 4 + half, p3 = beg + 6 + half;
                int r0 = (p0 < end) ? srcs[p0] : N;
                int r1 = (p1 < end) ? srcs[p1] : N;
                int r2 = (p2 < end) ? srcs[p2] : N;
                int r3 = (p3 < end) ? srcs[p3] : N;
                for (int e = beg; e < end; e += 8) {
                    uint4 q0 = h[(size_t)r0 * 32 + c];
                    uint4 q1 = h[(size_t)r1 * 32 + c];
                    uint4 q2 = h[(size_t)r2 * 32 + c];
                    uint4 q3 = h[(size_t)r3 * 32 + c];
                    p0 += 8; p1 += 8; p2 += 8; p3 += 8;
                    int n0 = (p0 < end) ? srcs[p0] : N;
                    int n1 = (p1 < end) ? srcs[p1] : N;
                    int n2 = (p2 < end) ? srcs[p2] : N;
                    int n3 = (p3 < end) ? srcs[p3] : N;
                    acc8a(acc, q0);
                    acc8a(acc, q1);
                    acc8a(acc, q2);
                    acc8a(acc, q3);
                    r0 = n0; r1 = n1; r2 = n2; r3 = n3;
                }
            }
        }
#pragma unroll
        for (int k = 0; k < 8; ++k) acc[k] += __shfl_xor(acc[k], 32, 64);

        if (half == 0) {
            float dvd = (node < N) ? dv[node] : 0.f;
            float4 b0 = *(const float4*)&bias[c * 8];
            float4 b1 = *(const float4*)&bias[c * 8 + 4];
            unsigned int o0 = f2bf(fmaxf(acc[0] * dvd + b0.x, 0.f));
            unsigned int o1 = f2bf(fmaxf(acc[1] * dvd + b0.y, 0.f));
            unsigned int o2 = f2bf(fmaxf(acc[2] * dvd + b0.z, 0.f));
            unsigned int o3 = f2bf(fmaxf(acc[3] * dvd + b0.w, 0.f));
            unsigned int o4 = f2bf(fmaxf(acc[4] * dvd + b1.x, 0.f));
            unsigned int o5 = f2bf(fmaxf(acc[5] * dvd + b1.y, 0.f));
            unsigned int o6 = f2bf(fmaxf(acc[6] * dvd + b1.z, 0.f));
            unsigned int o7 = f2bf(fmaxf(acc[7] * dvd + b1.w, 0.f));
            uint4 ov;
            ov.x = o0 | (o1 << 16);
            ov.y = o2 | (o3 << 16);
            ov.z = o4 | (o5 << 16);
            ov.w = o6 | (o7 << 16);
            *(uint4*)&As[local][c * 8] = ov;
        }
    }
    __syncthreads();

    // Phase 2: D[16 nodes][64 cols] = As[16][256] @ W2t^T; pre-scale by dv.
    const int quad = lane >> 4, l15 = lane & 15;
    f32x4 accd = {};
#pragma unroll
    for (int k0 = 0; k0 < 8; ++k0) {
        bf16x8 af = *(const bf16x8*)&As[l15][k0 * 32 + quad * 8];
        bf16x8 bf = *(const bf16x8*)&W2t[(size_t)(wave * 16 + l15) * 256 +
                                         k0 * 32 + quad * 8];
        accd = __builtin_amdgcn_mfma_f32_16x16x32_bf16(af, bf, accd, 0, 0, 0);
    }
#pragma unroll
    for (int r = 0; r < 4; ++r) {
        int node = node0 + quad * 4 + r;
        if (node < N)
            h2s[(size_t)node * 64 + wave * 16 + l15] =
                f2bf(accd[r] * dv[node]);
    }
}

// ---- out = log_softmax(dv_d * (A h2s) + b2), F=64 -------------------------
__global__ __launch_bounds__(256) void agg64_kernel(
    const uint4* __restrict__ h,  // h2s rows = 8 uint4 (64 bf16), N+1 rows
    const int* __restrict__ srcs, const int* __restrict__ row_ptr,
    const float* __restrict__ dv, const float* __restrict__ bias,
    float* __restrict__ out, int N) {
    const int node = blockIdx.x * 4 + (threadIdx.x >> 6);
    if (node >= N) return;
    const int lane = threadIdx.x & 63;
    const int g = lane >> 3;
    const int c = lane & 7;

    float acc[8] = {0.f, 0.f, 0.f, 0.f, 0.f, 0.f, 0.f, 0.f};
    {   // self: group 0 real row (weight 1), others zero row
        uint4 q = h[(size_t)(g == 0 ? node : N) * 8 + c];
        acc8a(acc, q);
    }

    const int beg = row_ptr[node], end = row_ptr[node + 1];
    if (beg < end) {
        int p0 = beg + g, p1 = beg + 8 + g;
        int r0 = (p0 < end) ? srcs[p0] : N;
        int r1 = (p1 < end) ? srcs[p1] : N;
        for (int e = beg; e < end; e += 16) {
            uint4 q0 = h[(size_t)r0 * 8 + c];
            uint4 q1 = h[(size_t)r1 * 8 + c];
            p0 += 16; p1 += 16;
            int n0 = (p0 < end) ? srcs[p0] : N;
            int n1 = (p1 < end) ? srcs[p1] : N;
            acc8a(acc, q0);
            acc8a(acc, q1);
            r0 = n0; r1 = n1;
        }
    }

#pragma unroll
    for (int k = 0; k < 8; ++k) {
        acc[k] += __shfl_xor(acc[k], 8, 64);
        acc[k] += __shfl_xor(acc[k], 16, 64);
        acc[k] += __shfl_xor(acc[k], 32, 64);
    }

    float dvd = dv[node];
    float4 b0 = *(const float4*)&bias[c * 8];
    float4 b1 = *(const float4*)&bias[c * 8 + 4];
    float v[8];
    v[0] = acc[0] * dvd + b0.x; v[1] = acc[1] * dvd + b0.y;
    v[2] = acc[2] * dvd + b0.z; v[3] = acc[3] * dvd + b0.w;
    v[4] = acc[4] * dvd + b1.x; v[5] = acc[5] * dvd + b1.y;
    v[6] = acc[6] * dvd + b1.z; v[7] = acc[7] * dvd + b1.w;

    float m = v[0];
#pragma unroll
    for (int k = 1; k < 8; ++k) m = fmaxf(m, v[k]);
    m = fmaxf(m, __shfl_xor(m, 1, 64));
    m = fmaxf(m, __shfl_xor(m, 2, 64));
    m = fmaxf(m, __shfl_xor(m, 4, 64));
    float s = 0.f;
#pragma unroll
    for (int k = 0; k < 8; ++k) s += expf(v[k] - m);
    s += __shfl_xor(s, 1, 64);
    s += __shfl_xor(s, 2, 64);
    s += __shfl_xor(s, 4, 64);
    float ls = m + logf(s);

    if (g == 0) {
        float4 o0, o1;
        o0.x = v[0] - ls; o0.y = v[1] - ls; o0.z = v[2] - ls; o0.w = v[3] - ls;
        o1.x = v[4] - ls; o1.y = v[5] - ls; o1.z = v[6] - ls; o1.w = v[7] - ls;
        *(float4*)&out[(size_t)node * 64 + c * 8] = o0;
        *(float4*)&out[(size_t)node * 64 + c * 8 + 4] = o1;
    }
}

extern "C" void kernel_launch(void* const* d_in, const int* in_sizes, int n_in,
                              void* d_out, int out_size, void* d_ws, size_t ws_size,
                              hipStream_t stream) {
    const float* x  = (const float*)d_in[0];
    const int*   ei = (const int*)d_in[1];
    const float* W1 = (const float*)d_in[2];
    const float* b1 = (const float*)d_in[3];
    const float* W2 = (const float*)d_in[4];
    const float* b2 = (const float*)d_in[5];
    float* out = (float*)d_out;

    const int N = in_sizes[0] / 256;  // 100000
    const int E = in_sizes[1] / 2;    // 1600000
    const int NP = 102400;
    const int NB = (N + 1023) / 1024;  // scan blocks (98)

    // Workspace layout (bytes; 16B-aligned segments). Total ~78 MB.
    char* ws = (char*)d_ws;
    int*   cnt     = (int*)ws;                 ws += (size_t)NP * 4;
    int*   rank    = (int*)ws;                 ws += (size_t)E * 4;
    int*   row_ptr = (int*)ws;                 ws += (size_t)(NP + 4) * 4;
    int*   bsum    = (int*)ws;                 ws += (size_t)1024 * 4;
    int*   boffs   = (int*)ws;                 ws += (size_t)1024 * 4;
    int*   csr_src = (int*)ws;                 ws += (size_t)(E + 16) * 4;
    unsigned short* W1t = (unsigned short*)ws; ws += (size_t)256 * 256 * 2;
    unsigned short* W2t = (unsigned short*)ws; ws += (size_t)256 * 64 * 2;
    float* dv = (float*)ws;                    ws += (size_t)NP * 4;
    unsigned short* h1s = (unsigned short*)ws; ws += (size_t)(N + 1) * 256 * 2;
    unsigned short* h2s = (unsigned short*)ws; ws += (size_t)(N + 1) * 64 * 2;

    hipMemsetAsync(cnt, 0, (size_t)N * sizeof(int), stream);

    // CSR build (one atomic pass; scatter is atomic-free)
    deg_rank_kernel<<<(E + 255) / 256, 256, 0, stream>>>(ei + E, E, cnt, rank);
    scan_part1_kernel<<<NB, 256, 0, stream>>>(cnt, bsum, N);
    scan_part2_kernel<<<1, 1024, 0, stream>>>(bsum, boffs, NB, row_ptr, N);
    scan_part3_kernel<<<NB, 256, 0, stream>>>(cnt, boffs, row_ptr, dv, N);
    scatter_kernel<<<(E + 255) / 256, 256, 0, stream>>>(
        ei, ei + E, rank, row_ptr, csr_src, E);

    // weight casts + pad-row zeroing (321st block)
    castw_kernel<<<321, 256, 0, stream>>>(W1, W2, W1t, W2t, h1s, h2s, N);

    // h1s = bf16(dv_row * (x @ W1))
    gemm1_kernel<<<(N + 127) / 128, 256, 0, stream>>>(x, W1t, dv, h1s, N);

    // h2s = bf16( dv_n * (relu(dv_n * (A h1s) + b1) @ W2) )  [fused]
    aggfused_kernel<<<(N + 15) / 16, 256, 0, stream>>>(
        (const uint4*)h1s, csr_src, row_ptr, dv, b1, W2t, h2s, N);

    // out = log_softmax(dv_d * (A h2s) + b2)
    agg64_kernel<<<(N + 3) / 4, 256, 0, stream>>>(
        (const uint4*)h2s, csr_src, row_ptr, dv, b2, out, N);
}